// Round 9
// baseline (826.161 us; speedup 1.0000x reference)
//
#include <hip/hip_runtime.h>

#define NN 40000
#define EE 400000

typedef short short8 __attribute__((ext_vector_type(8)));
typedef float f32x4 __attribute__((ext_vector_type(4)));
typedef unsigned short ushort4_ __attribute__((ext_vector_type(4)));

__device__ __forceinline__ unsigned short f2bf(float f) {
  unsigned int u = __float_as_uint(f);
  u = (u + 0x7FFFu + ((u >> 16) & 1u)) >> 16;
  return (unsigned short)u;
}

__device__ __forceinline__ short8 cvt8(f32x4 a, f32x4 b) {
  short8 r;
  r[0] = (short)f2bf(a[0]); r[1] = (short)f2bf(a[1]);
  r[2] = (short)f2bf(a[2]); r[3] = (short)f2bf(a[3]);
  r[4] = (short)f2bf(b[0]); r[5] = (short)f2bf(b[1]);
  r[6] = (short)f2bf(b[2]); r[7] = (short)f2bf(b[3]);
  return r;
}

__device__ __forceinline__ f32x4 ld_bf4(const unsigned short* p) {
  ushort4_ u = *(const ushort4_*)p;
  f32x4 r;
  r[0] = __uint_as_float((unsigned int)u[0] << 16);
  r[1] = __uint_as_float((unsigned int)u[1] << 16);
  r[2] = __uint_as_float((unsigned int)u[2] << 16);
  r[3] = __uint_as_float((unsigned int)u[3] << 16);
  return r;
}

__device__ __forceinline__ float lrelu(float v) { return v >= 0.f ? v : 0.2f * v; }

// ---- fused prep: wt2 (bf16 W, k-tiled) + weffb (bf16 W·att, B layout) -----
// wt2[r][kt][n][k0] = W[r][kt*32+k0][n]   (262144 elems)
// weffb[kt][col][k0] = bf16(sum_c W[r][f][j*32+c]*att[r][j][c]), col=q*8+j,
//   f=kt*32+k0, q=r*2+side                 (16384 elems)
__global__ __launch_bounds__(256) void k_prep(const float* __restrict__ W,
                                              const float* __restrict__ asrc,
                                              const float* __restrict__ adst,
                                              unsigned short* __restrict__ wt2,
                                              unsigned short* __restrict__ weffb) {
  int idx = blockIdx.x * 256 + threadIdx.x;
  if (idx < 262144) {
    int k0 = idx & 31, n = (idx >> 5) & 255, kt = (idx >> 13) & 7, r = idx >> 16;
    wt2[idx] = f2bf(W[((size_t)(r * 256) + (kt * 32 + k0)) * 256 + n]);
  } else if (idx < 262144 + 16384) {
    int id2 = idx - 262144;
    int k0 = id2 & 31, col = (id2 >> 5) & 63, kt = id2 >> 11;
    int q = col >> 3, j = col & 7;
    int r = q >> 1, side = q & 1;
    int f = kt * 32 + k0;
    const float* att = side ? adst : asrc;
    const float* wrow = W + ((size_t)(r * 256) + f) * 256 + j * 32;
    const float* arow = att + (r * 8 + j) * 32;
    float s = 0.f;
#pragma unroll
    for (int c = 0; c < 32; ++c) s += wrow[c] * arow[c];
    weffb[id2] = f2bf(s);
  }
}

// ---- CSR build ------------------------------------------------------------
__global__ __launch_bounds__(256) void k_zero(int* __restrict__ p, int n) {
  int i = blockIdx.x * 256 + threadIdx.x;
  if (i < n) p[i] = 0;
}

__global__ __launch_bounds__(256) void k_hist(
    const int* __restrict__ e0, const int* __restrict__ e1,
    const int* __restrict__ e2, const int* __restrict__ e3, int* __restrict__ cnt) {
  int r = blockIdx.y;
  const int* ei = (r == 0) ? e0 : (r == 1) ? e1 : (r == 2) ? e2 : e3;
  int e = blockIdx.x * 256 + threadIdx.x;
  if (e < EE) atomicAdd(&cnt[r * NN + ei[EE + e]], 1);
}

__global__ __launch_bounds__(1024) void k_scan(const int* __restrict__ cnt,
                                               int* __restrict__ rowptr,
                                               int* __restrict__ cursor) {
  int r = blockIdx.x;
  const int* c = cnt + r * NN;
  int* rp = rowptr + r * (NN + 1);
  int* cur = cursor + r * NN;
  __shared__ int part[1024];
  int t = threadIdx.x;
  const int per = 40;  // 1024*40 >= 40000
  int base = t * per;
  int sum = 0;
  for (int i = 0; i < per; ++i) { int idx = base + i; if (idx < NN) sum += c[idx]; }
  part[t] = sum;
  __syncthreads();
  for (int o = 1; o < 1024; o <<= 1) {
    int v = (t >= o) ? part[t - o] : 0;
    __syncthreads();
    part[t] += v;
    __syncthreads();
  }
  int run = part[t] - sum;  // exclusive prefix
  for (int i = 0; i < per; ++i) {
    int idx = base + i;
    if (idx < NN) { rp[idx] = run; cur[idx] = run; run += c[idx]; }
  }
  if (t == 1023) rp[NN] = part[1023];
}

__global__ __launch_bounds__(256) void k_scatter(
    const int* __restrict__ e0, const int* __restrict__ e1,
    const int* __restrict__ e2, const int* __restrict__ e3,
    int* __restrict__ cursor, int* __restrict__ adj) {
  int r = blockIdx.y;
  const int* ei = (r == 0) ? e0 : (r == 1) ? e1 : (r == 2) ? e2 : e3;
  int e = blockIdx.x * 256 + threadIdx.x;
  if (e < EE) {
    int s = ei[e], d = ei[EE + e];
    int pos = atomicAdd(&cursor[r * NN + d], 1);
    adj[(size_t)r * EE + pos] = s;
  }
}

// ---- logits, (h,g)-paired: alpf[t][q][n][h][g] = bf16(x) @ weffb ----------
__global__ __launch_bounds__(256) void k_algemm(
    const float* __restrict__ x0, const float* __restrict__ x1, const float* __restrict__ x2,
    const float* __restrict__ x3, const float* __restrict__ x4, const float* __restrict__ x5,
    const unsigned short* __restrict__ weffb, float* __restrict__ alpf) {
  __shared__ __attribute__((aligned(16))) unsigned short Alds[64][40];
  __shared__ __attribute__((aligned(16))) unsigned short Blds[64][40];
  int z = blockIdx.y;
  int g = (z >= 3) ? 1 : 0, ty = z - g * 3;
  const float* xp;
  switch (z) { case 0: xp = x0; break; case 1: xp = x1; break; case 2: xp = x2; break;
               case 3: xp = x3; break; case 4: xp = x4; break; default: xp = x5; break; }
  int tid = threadIdx.x;
  int wave = tid >> 6, lane = tid & 63;
  int l15 = lane & 15, l16 = lane >> 4;
  int row0 = blockIdx.x * 64;
  f32x4 acc[4] = {};
  int ar = tid >> 2, ac = (tid & 3) * 8;
  const float* aglob = xp + (size_t)(row0 + ar) * 256 + ac;
  for (int kt = 0; kt < 8; ++kt) {
    f32x4 a0 = *(const f32x4*)(aglob + kt * 32);
    f32x4 a1 = *(const f32x4*)(aglob + kt * 32 + 4);
    *(short8*)(&Alds[ar][ac]) = cvt8(a0, a1);
    short8 bv = *(const short8*)(weffb + kt * 2048 + tid * 8);
    *(short8*)(&Blds[tid >> 2][(tid & 3) * 8]) = bv;
    __syncthreads();
    short8 bf = *(const short8*)(&Blds[wave * 16 + l15][l16 * 8]);
#pragma unroll
    for (int mt = 0; mt < 4; ++mt) {
      short8 af = *(const short8*)(&Alds[mt * 16 + l15][l16 * 8]);
      acc[mt] = __builtin_amdgcn_mfma_f32_16x16x32_bf16(af, bf, acc[mt], 0, 0, 0);
    }
    __syncthreads();
  }
  int col = wave * 16 + l15;
  int q = col >> 3, jj = col & 7;
#pragma unroll
  for (int mt = 0; mt < 4; ++mt)
#pragma unroll
    for (int rr = 0; rr < 4; ++rr) {
      int row = row0 + mt * 16 + l16 * 4 + rr;
      alpf[((size_t)(ty * 8 + q) * NN + row) * 16 + jj * 2 + g] = acc[mt][rr];
    }
}

// ---- per-head global max of alsrc column ----------------------------------
__global__ __launch_bounds__(256) void k_maxsrcp(const float* __restrict__ alpf,
                                                 float* __restrict__ pmax) {
  const int srct[4] = {0, 1, 0, 2};
  int gr = blockIdx.x, slice = blockIdx.y;
  int g = gr >> 2, r = gr & 3;
  const float* col = alpf + ((size_t)(srct[r] * 8 + 2 * r) * NN) * 16;
  int t = threadIdx.x;
  int h = t & 7, chunk = t >> 3;  // 32 chunks
  float m = -1e30f;
  for (int nn = chunk; nn < 1250; nn += 32)
    m = fmaxf(m, col[(size_t)(slice * 1250 + nn) * 16 + h * 2 + g]);
  __shared__ float red[256];
  red[t] = m;
  __syncthreads();
  for (int o = 128; o >= 8; o >>= 1) {
    if (t < o) red[t] = fmaxf(red[t], red[t + o]);
    __syncthreads();
  }
  if (t < 8) pmax[(gr * 32 + slice) * 8 + t] = red[t];
}

__global__ __launch_bounds__(64) void k_maxfin(const float* __restrict__ pmax,
                                               float* __restrict__ maxsrc) {
  int t = threadIdx.x;  // 64 = 8 gr * 8 h
  int gr = t >> 3, h = t & 7;
  float m = -1e30f;
  for (int s = 0; s < 32; ++s) m = fmaxf(m, pmax[(gr * 32 + s) * 8 + h]);
  maxsrc[t] = m;
}

// ---- bf16 MFMA GEMM, BK=64: hbi[r][n][g][256] = bf16(x @ W) ---------------
__global__ __launch_bounds__(256) void k_gemmb8(
    const float* __restrict__ x0, const float* __restrict__ x1, const float* __restrict__ x2,
    const float* __restrict__ x3, const float* __restrict__ x4, const float* __restrict__ x5,
    const unsigned short* __restrict__ wt2, unsigned short* __restrict__ hbi) {
  __shared__ __attribute__((aligned(16))) unsigned short A0lds[64][40];
  __shared__ __attribute__((aligned(16))) unsigned short A1lds[64][40];
  __shared__ __attribute__((aligned(16))) unsigned short B0lds[256][40];
  __shared__ __attribute__((aligned(16))) unsigned short B1lds[256][40];
  const int srct[4] = {0, 1, 0, 2};
  int y = blockIdx.y;  // g*4 + r
  int g = y >> 2, r = y & 3;
  int t6 = g * 3 + srct[r];
  const float* xp;
  switch (t6) { case 0: xp = x0; break; case 1: xp = x1; break; case 2: xp = x2; break;
                case 3: xp = x3; break; case 4: xp = x4; break; default: xp = x5; break; }
  const unsigned short* wtp = wt2 + (size_t)r * (8 * 256 * 32);
  int tid = threadIdx.x;
  int wave = tid >> 6, lane = tid & 63;
  int l15 = lane & 15, l16 = lane >> 4;
  int row0 = blockIdx.x * 64;
  f32x4 acc[4][4] = {};
  int ar = tid >> 2, ac = (tid & 3) * 16;  // 16 floats per thread per kstep
  const float* aglob = xp + (size_t)(row0 + ar) * 256 + ac;
  for (int ks = 0; ks < 4; ++ks) {
    f32x4 a0 = *(const f32x4*)(aglob + ks * 64);
    f32x4 a1 = *(const f32x4*)(aglob + ks * 64 + 4);
    f32x4 a2 = *(const f32x4*)(aglob + ks * 64 + 8);
    f32x4 a3 = *(const f32x4*)(aglob + ks * 64 + 12);
    if (ac < 32) {
      *(short8*)(&A0lds[ar][ac]) = cvt8(a0, a1);
      *(short8*)(&A0lds[ar][ac + 8]) = cvt8(a2, a3);
    } else {
      *(short8*)(&A1lds[ar][ac - 32]) = cvt8(a0, a1);
      *(short8*)(&A1lds[ar][ac - 24]) = cvt8(a2, a3);
    }
    const unsigned short* b0 = wtp + (2 * ks) * 8192;
    const unsigned short* b1 = wtp + (2 * ks + 1) * 8192;
#pragma unroll
    for (int i = 0; i < 4; ++i) {
      int cidx = tid + 256 * i;
      *(short8*)(&B0lds[cidx >> 2][(cidx & 3) * 8]) = *(const short8*)(b0 + cidx * 8);
      *(short8*)(&B1lds[cidx >> 2][(cidx & 3) * 8]) = *(const short8*)(b1 + cidx * 8);
    }
    __syncthreads();
#pragma unroll
    for (int kk = 0; kk < 2; ++kk) {
      short8 af[4], bf[4];
#pragma unroll
      for (int mt = 0; mt < 4; ++mt)
        af[mt] = kk ? *(const short8*)(&A1lds[mt * 16 + l15][l16 * 8])
                    : *(const short8*)(&A0lds[mt * 16 + l15][l16 * 8]);
#pragma unroll
      for (int nt = 0; nt < 4; ++nt)
        bf[nt] = kk ? *(const short8*)(&B1lds[wave * 64 + nt * 16 + l15][l16 * 8])
                    : *(const short8*)(&B0lds[wave * 64 + nt * 16 + l15][l16 * 8]);
#pragma unroll
      for (int mt = 0; mt < 4; ++mt)
#pragma unroll
        for (int nt = 0; nt < 4; ++nt)
          acc[mt][nt] = __builtin_amdgcn_mfma_f32_16x16x32_bf16(af[mt], bf[nt], acc[mt][nt], 0, 0, 0);
    }
    __syncthreads();
  }
#pragma unroll
  for (int mt = 0; mt < 4; ++mt)
#pragma unroll
    for (int nt = 0; nt < 4; ++nt)
#pragma unroll
      for (int rr = 0; rr < 4; ++rr) {
        int row = row0 + mt * 16 + l16 * 4 + rr;
        hbi[((size_t)(r * NN + row) * 2 + g) * 256 + wave * 64 + nt * 16 + l15] =
            f2bf(acc[mt][nt][rr]);
      }
}

// ---- one-relation aggregation for BOTH graphs, 16-edge groups -------------
__device__ __forceinline__ void agg_one2(
    int r, int d, int lane,
    const int* __restrict__ rowptr4, const int* __restrict__ adj4,
    const float* __restrict__ alpf, const unsigned short* __restrict__ hbi,
    const float* __restrict__ maxsrc, f32x4& o0, f32x4& o1) {
  const int srct[4] = {0, 1, 0, 2};
  const int dstt[4] = {1, 0, 2, 0};
  int h = lane >> 3, e8 = lane & 7, ob = lane & 56;
  const int* rowptr = rowptr4 + r * (NN + 1);
  const int* adj = adj4 + (size_t)r * EE;
  const float* asb = alpf + ((size_t)(srct[r] * 8 + 2 * r) * NN) * 16;
  const float* adb = alpf + ((size_t)(dstt[r] * 8 + 2 * r + 1) * NN) * 16;
  const unsigned short* hbr = hbi + (size_t)(r * NN) * 512;

  int beg = rowptr[d], end = rowptr[d + 1];
  float2 adp = *(const float2*)(adb + (size_t)d * 16 + h * 2);
  float adst0 = adp.x, adst1 = adp.y;
  float ub0 = lrelu(maxsrc[r * 8 + h] + adst0);       // exact segment upper bound
  float ub1 = lrelu(maxsrc[(4 + r) * 8 + h] + adst1);
  float2 asp = *(const float2*)(asb + (size_t)d * 16 + h * 2);
  float ws0 = __expf(lrelu(asp.x + adst0) - ub0);
  float ws1 = __expf(lrelu(asp.y + adst1) - ub1);
  float ssum0 = (e8 == 0) ? ws0 : 0.0f;
  float ssum1 = (e8 == 0) ? ws1 : 0.0f;
  const unsigned short* selfrow = hbr + (size_t)d * 512;
  f32x4 hv0 = ld_bf4(selfrow + lane * 4);
  f32x4 hv1 = ld_bf4(selfrow + 256 + lane * 4);
  f32x4 acc0, acc1;
#pragma unroll
  for (int i = 0; i < 4; ++i) { acc0[i] = ws0 * hv0[i]; acc1[i] = ws1 * hv1[i]; }

  for (int j0 = beg; j0 < end; j0 += 16) {
    int ja = j0 + e8, jb = ja + 8;
    bool va = ja < end, vb = jb < end;
    int sa = va ? adj[ja] : d;
    int sb = vb ? adj[jb] : d;
    float2 la = *(const float2*)(asb + (size_t)sa * 16 + h * 2);
    float2 lb = *(const float2*)(asb + (size_t)sb * 16 + h * 2);
    float w0a = va ? __expf(lrelu(la.x + adst0) - ub0) : 0.f;
    float w1a = va ? __expf(lrelu(la.y + adst1) - ub1) : 0.f;
    float w0b = vb ? __expf(lrelu(lb.x + adst0) - ub0) : 0.f;
    float w1b = vb ? __expf(lrelu(lb.y + adst1) - ub1) : 0.f;
    ssum0 += w0a + w0b;
    ssum1 += w1a + w1b;
#pragma unroll
    for (int e2 = 0; e2 < 16; ++e2) {
      int se = __shfl(e2 < 8 ? sa : sb, ob + (e2 & 7), 64);
      float w0e = __shfl(e2 < 8 ? w0a : w0b, ob + (e2 & 7), 64);
      float w1e = __shfl(e2 < 8 ? w1a : w1b, ob + (e2 & 7), 64);
      const unsigned short* row = hbr + (size_t)se * 512;
      f32x4 g0 = ld_bf4(row + lane * 4);
      f32x4 g1 = ld_bf4(row + 256 + lane * 4);
#pragma unroll
      for (int i = 0; i < 4; ++i) { acc0[i] += w0e * g0[i]; acc1[i] += w1e * g1[i]; }
    }
  }
  ssum0 += __shfl_xor(ssum0, 1, 64);
  ssum0 += __shfl_xor(ssum0, 2, 64);
  ssum0 += __shfl_xor(ssum0, 4, 64);
  ssum1 += __shfl_xor(ssum1, 1, 64);
  ssum1 += __shfl_xor(ssum1, 2, 64);
  ssum1 += __shfl_xor(ssum1, 4, 64);
  float i0 = 1.f / ssum0, i1 = 1.f / ssum1;
#pragma unroll
  for (int i = 0; i < 4; ++i) { o0[i] = acc0[i] * i0; o1[i] = acc1[i] * i1; }
}

// ---- persistent-wave aggregation, both graphs per item --------------------
#define AGG_BLOCKS 1875
__global__ __launch_bounds__(256) void k_agg6(
    const int* __restrict__ rowptr4, const int* __restrict__ adj4,
    const float* __restrict__ alpf, const unsigned short* __restrict__ hbi,
    const float* __restrict__ bias, const float* __restrict__ maxsrc,
    float* __restrict__ out) {
  int lane = threadIdx.x & 63;
  int wgid = (blockIdx.x * 256 + (int)threadIdx.x) >> 6;
  const int NWV = AGG_BLOCKS * 4;
  for (int item = wgid; item < 3 * NN; item += NWV) {
    int y = item / NN;
    int d = item - y * NN;
    f32x4 r0g0, r0g1, r1g0, r1g1;
    int sec;
    if (y == 1) {
      agg_one2(1, d, lane, rowptr4, adj4, alpf, hbi, maxsrc, r0g0, r0g1);
      agg_one2(3, d, lane, rowptr4, adj4, alpf, hbi, maxsrc, r1g0, r1g1);
      f32x4 b1 = *(const f32x4*)(bias + 1 * 256 + lane * 4);
      f32x4 b3 = *(const f32x4*)(bias + 3 * 256 + lane * 4);
#pragma unroll
      for (int i = 0; i < 4; ++i) {
        r0g0[i] = 0.5f * (r0g0[i] + b1[i] + r1g0[i] + b3[i]);
        r0g1[i] = 0.5f * (r0g1[i] + b1[i] + r1g1[i] + b3[i]);
      }
      sec = 0;
    } else {
      int r = (y == 0) ? 0 : 2;
      agg_one2(r, d, lane, rowptr4, adj4, alpf, hbi, maxsrc, r0g0, r0g1);
      f32x4 bv = *(const f32x4*)(bias + r * 256 + lane * 4);
#pragma unroll
      for (int i = 0; i < 4; ++i) { r0g0[i] += bv[i]; r0g1[i] += bv[i]; }
      sec = (y == 0) ? 1 : 2;
    }
    f32x4* op0 = (f32x4*)(out + ((size_t)(0 + sec) * NN + d) * 256 + lane * 4);
    f32x4* op1 = (f32x4*)(out + ((size_t)(3 + sec) * NN + d) * 256 + lane * 4);
    __builtin_nontemporal_store(r0g0, op0);
    __builtin_nontemporal_store(r0g1, op1);
  }
}

extern "C" void kernel_launch(void* const* d_in, const int* in_sizes, int n_in,
                              void* d_out, int out_size, void* d_ws, size_t ws_size,
                              hipStream_t stream) {
  (void)in_sizes; (void)n_in; (void)out_size; (void)ws_size;
  const float* x[6];
  for (int i = 0; i < 6; ++i) x[i] = (const float*)d_in[i];
  const float* W = (const float*)d_in[6];
  const float* att_src = (const float*)d_in[7];
  const float* att_dst = (const float*)d_in[8];
  const float* bias = (const float*)d_in[9];
  const int* ei[4] = {(const int*)d_in[10], (const int*)d_in[11],
                      (const int*)d_in[12], (const int*)d_in[13]};
  float* out = (float*)d_out;

  char* ws = (char*)d_ws;
  size_t off = 0;
  auto take = [&](size_t bytes) -> char* {
    char* p = ws + off;
    off += (bytes + 255) & ~(size_t)255;
    return p;
  };
  unsigned short* hbi = (unsigned short*)take(8ull * NN * 256 * 2);   // 163.8 MB
  float* alpf = (float*)take(3ull * 8 * NN * 16 * 4);                 // 61.4 MB
  unsigned short* wt2 = (unsigned short*)take(4ull * 8 * 256 * 32 * 2);
  unsigned short* weffb = (unsigned short*)take(8ull * 64 * 32 * 2);
  int* cnt = (int*)take(4ull * NN * 4);
  int* rowptr = (int*)take(4ull * (NN + 1) * 4);
  int* cursor = (int*)take(4ull * NN * 4);
  int* adj = (int*)take(4ull * EE * 4);
  float* pmax = (float*)take(8ull * 32 * 8 * 4);
  float* maxsrc = (float*)take(64ull * 4);

  k_prep<<<dim3(1088), 256, 0, stream>>>(W, att_src, att_dst, wt2, weffb);
  k_zero<<<dim3(625), 256, 0, stream>>>(cnt, 4 * NN);
  k_hist<<<dim3((EE + 255) / 256, 4), 256, 0, stream>>>(ei[0], ei[1], ei[2], ei[3], cnt);
  k_scan<<<dim3(4), 1024, 0, stream>>>(cnt, rowptr, cursor);
  k_scatter<<<dim3((EE + 255) / 256, 4), 256, 0, stream>>>(ei[0], ei[1], ei[2], ei[3], cursor, adj);
  k_algemm<<<dim3(625, 6), 256, 0, stream>>>(x[0], x[1], x[2], x[3], x[4], x[5],
                                             weffb, alpf);
  k_maxsrcp<<<dim3(8, 32), 256, 0, stream>>>(alpf, pmax);
  k_maxfin<<<dim3(1), 64, 0, stream>>>(pmax, maxsrc);
  k_gemmb8<<<dim3(625, 8), 256, 0, stream>>>(x[0], x[1], x[2], x[3], x[4], x[5],
                                             wt2, hbi);
  k_agg6<<<dim3(AGG_BLOCKS), 256, 0, stream>>>(rowptr, adj, alpf, hbi, bias, maxsrc, out);
}

// Round 10
// 822.581 us; speedup vs baseline: 1.0044x; 1.0044x over previous
//
#include <hip/hip_runtime.h>

#define NN 40000
#define EE 400000

typedef short short8 __attribute__((ext_vector_type(8)));
typedef float f32x4 __attribute__((ext_vector_type(4)));
typedef unsigned short ushort4_ __attribute__((ext_vector_type(4)));

__device__ __forceinline__ unsigned short f2bf(float f) {
  unsigned int u = __float_as_uint(f);
  u = (u + 0x7FFFu + ((u >> 16) & 1u)) >> 16;
  return (unsigned short)u;
}

__device__ __forceinline__ short8 cvt8(f32x4 a, f32x4 b) {
  short8 r;
  r[0] = (short)f2bf(a[0]); r[1] = (short)f2bf(a[1]);
  r[2] = (short)f2bf(a[2]); r[3] = (short)f2bf(a[3]);
  r[4] = (short)f2bf(b[0]); r[5] = (short)f2bf(b[1]);
  r[6] = (short)f2bf(b[2]); r[7] = (short)f2bf(b[3]);
  return r;
}

__device__ __forceinline__ f32x4 ld_bf4(const unsigned short* p) {
  ushort4_ u = *(const ushort4_*)p;
  f32x4 r;
  r[0] = __uint_as_float((unsigned int)u[0] << 16);
  r[1] = __uint_as_float((unsigned int)u[1] << 16);
  r[2] = __uint_as_float((unsigned int)u[2] << 16);
  r[3] = __uint_as_float((unsigned int)u[3] << 16);
  return r;
}

__device__ __forceinline__ float lrelu(float v) { return v >= 0.f ? v : 0.2f * v; }

// ---- fused prep: wt2 (bf16 W, k-tiled) + weffb (bf16 W·att, B layout) -----
__global__ __launch_bounds__(256) void k_prep(const float* __restrict__ W,
                                              const float* __restrict__ asrc,
                                              const float* __restrict__ adst,
                                              unsigned short* __restrict__ wt2,
                                              unsigned short* __restrict__ weffb) {
  int idx = blockIdx.x * 256 + threadIdx.x;
  if (idx < 262144) {
    int k0 = idx & 31, n = (idx >> 5) & 255, kt = (idx >> 13) & 7, r = idx >> 16;
    wt2[idx] = f2bf(W[((size_t)(r * 256) + (kt * 32 + k0)) * 256 + n]);
  } else if (idx < 262144 + 16384) {
    int id2 = idx - 262144;
    int k0 = id2 & 31, col = (id2 >> 5) & 63, kt = id2 >> 11;
    int q = col >> 3, j = col & 7;
    int r = q >> 1, side = q & 1;
    int f = kt * 32 + k0;
    const float* att = side ? adst : asrc;
    const float* wrow = W + ((size_t)(r * 256) + f) * 256 + j * 32;
    const float* arow = att + (r * 8 + j) * 32;
    float s = 0.f;
#pragma unroll
    for (int c = 0; c < 32; ++c) s += wrow[c] * arow[c];
    weffb[id2] = f2bf(s);
  }
}

// ---- CSR build ------------------------------------------------------------
__global__ __launch_bounds__(256) void k_hist(
    const int* __restrict__ e0, const int* __restrict__ e1,
    const int* __restrict__ e2, const int* __restrict__ e3, int* __restrict__ cnt) {
  int r = blockIdx.y;
  const int* ei = (r == 0) ? e0 : (r == 1) ? e1 : (r == 2) ? e2 : e3;
  int e = blockIdx.x * 256 + threadIdx.x;
  if (e < EE) atomicAdd(&cnt[r * NN + ei[EE + e]], 1);
}

__global__ __launch_bounds__(1024) void k_scan(const int* __restrict__ cnt,
                                               int* __restrict__ rowptr,
                                               int* __restrict__ cursor) {
  int r = blockIdx.x;
  const int* c = cnt + r * NN;
  int* rp = rowptr + r * (NN + 1);
  int* cur = cursor + r * NN;
  __shared__ int part[1024];
  int t = threadIdx.x;
  const int per = 40;  // 1024*40 >= 40000
  int base = t * per;
  int sum = 0;
  for (int i = 0; i < per; ++i) { int idx = base + i; if (idx < NN) sum += c[idx]; }
  part[t] = sum;
  __syncthreads();
  for (int o = 1; o < 1024; o <<= 1) {
    int v = (t >= o) ? part[t - o] : 0;
    __syncthreads();
    part[t] += v;
    __syncthreads();
  }
  int run = part[t] - sum;  // exclusive prefix
  for (int i = 0; i < per; ++i) {
    int idx = base + i;
    if (idx < NN) { rp[idx] = run; cur[idx] = run; run += c[idx]; }
  }
  if (t == 1023) rp[NN] = part[1023];
}

__global__ __launch_bounds__(256) void k_scatter(
    const int* __restrict__ e0, const int* __restrict__ e1,
    const int* __restrict__ e2, const int* __restrict__ e3,
    int* __restrict__ cursor, int* __restrict__ adj) {
  int r = blockIdx.y;
  const int* ei = (r == 0) ? e0 : (r == 1) ? e1 : (r == 2) ? e2 : e3;
  int e = blockIdx.x * 256 + threadIdx.x;
  if (e < EE) {
    int s = ei[e], d = ei[EE + e];
    int pos = atomicAdd(&cursor[r * NN + d], 1);
    adj[(size_t)r * EE + pos] = s;
  }
}

// ---- logits, (h,g)-paired: alpf[t][q][n][h][g] = bf16(x) @ weffb ----------
__global__ __launch_bounds__(256) void k_algemm(
    const float* __restrict__ x0, const float* __restrict__ x1, const float* __restrict__ x2,
    const float* __restrict__ x3, const float* __restrict__ x4, const float* __restrict__ x5,
    const unsigned short* __restrict__ weffb, float* __restrict__ alpf) {
  __shared__ __attribute__((aligned(16))) unsigned short Alds[64][40];
  __shared__ __attribute__((aligned(16))) unsigned short Blds[64][40];
  int z = blockIdx.y;
  int g = (z >= 3) ? 1 : 0, ty = z - g * 3;
  const float* xp;
  switch (z) { case 0: xp = x0; break; case 1: xp = x1; break; case 2: xp = x2; break;
               case 3: xp = x3; break; case 4: xp = x4; break; default: xp = x5; break; }
  int tid = threadIdx.x;
  int wave = tid >> 6, lane = tid & 63;
  int l15 = lane & 15, l16 = lane >> 4;
  int row0 = blockIdx.x * 64;
  f32x4 acc[4] = {};
  int ar = tid >> 2, ac = (tid & 3) * 8;
  const float* aglob = xp + (size_t)(row0 + ar) * 256 + ac;
  for (int kt = 0; kt < 8; ++kt) {
    f32x4 a0 = *(const f32x4*)(aglob + kt * 32);
    f32x4 a1 = *(const f32x4*)(aglob + kt * 32 + 4);
    *(short8*)(&Alds[ar][ac]) = cvt8(a0, a1);
    short8 bv = *(const short8*)(weffb + kt * 2048 + tid * 8);
    *(short8*)(&Blds[tid >> 2][(tid & 3) * 8]) = bv;
    __syncthreads();
    short8 bf = *(const short8*)(&Blds[wave * 16 + l15][l16 * 8]);
#pragma unroll
    for (int mt = 0; mt < 4; ++mt) {
      short8 af = *(const short8*)(&Alds[mt * 16 + l15][l16 * 8]);
      acc[mt] = __builtin_amdgcn_mfma_f32_16x16x32_bf16(af, bf, acc[mt], 0, 0, 0);
    }
    __syncthreads();
  }
  int col = wave * 16 + l15;
  int q = col >> 3, jj = col & 7;
#pragma unroll
  for (int mt = 0; mt < 4; ++mt)
#pragma unroll
    for (int rr = 0; rr < 4; ++rr) {
      int row = row0 + mt * 16 + l16 * 4 + rr;
      alpf[((size_t)(ty * 8 + q) * NN + row) * 16 + jj * 2 + g] = acc[mt][rr];
    }
}

// ---- per-head global max of alsrc column ----------------------------------
__global__ __launch_bounds__(256) void k_maxsrcp(const float* __restrict__ alpf,
                                                 float* __restrict__ pmax) {
  const int srct[4] = {0, 1, 0, 2};
  int gr = blockIdx.x, slice = blockIdx.y;
  int g = gr >> 2, r = gr & 3;
  const float* col = alpf + ((size_t)(srct[r] * 8 + 2 * r) * NN) * 16;
  int t = threadIdx.x;
  int h = t & 7, chunk = t >> 3;  // 32 chunks
  float m = -1e30f;
  for (int nn = chunk; nn < 1250; nn += 32)
    m = fmaxf(m, col[(size_t)(slice * 1250 + nn) * 16 + h * 2 + g]);
  __shared__ float red[256];
  red[t] = m;
  __syncthreads();
  for (int o = 128; o >= 8; o >>= 1) {
    if (t < o) red[t] = fmaxf(red[t], red[t + o]);
    __syncthreads();
  }
  if (t < 8) pmax[(gr * 32 + slice) * 8 + t] = red[t];
}

__global__ __launch_bounds__(64) void k_maxfin(const float* __restrict__ pmax,
                                               float* __restrict__ maxsrc) {
  int t = threadIdx.x;  // 64 = 8 gr * 8 h
  int gr = t >> 3, h = t & 7;
  float m = -1e30f;
  for (int s = 0; s < 32; ++s) m = fmaxf(m, pmax[(gr * 32 + s) * 8 + h]);
  maxsrc[t] = m;
}

// ---- bf16 MFMA GEMM, BK=64: hbi[r][n][g][256] = bf16(x @ W) ---------------
__global__ __launch_bounds__(256) void k_gemmb8(
    const float* __restrict__ x0, const float* __restrict__ x1, const float* __restrict__ x2,
    const float* __restrict__ x3, const float* __restrict__ x4, const float* __restrict__ x5,
    const unsigned short* __restrict__ wt2, unsigned short* __restrict__ hbi) {
  __shared__ __attribute__((aligned(16))) unsigned short A0lds[64][40];
  __shared__ __attribute__((aligned(16))) unsigned short A1lds[64][40];
  __shared__ __attribute__((aligned(16))) unsigned short B0lds[256][40];
  __shared__ __attribute__((aligned(16))) unsigned short B1lds[256][40];
  const int srct[4] = {0, 1, 0, 2};
  int y = blockIdx.y;  // g*4 + r
  int g = y >> 2, r = y & 3;
  int t6 = g * 3 + srct[r];
  const float* xp;
  switch (t6) { case 0: xp = x0; break; case 1: xp = x1; break; case 2: xp = x2; break;
                case 3: xp = x3; break; case 4: xp = x4; break; default: xp = x5; break; }
  const unsigned short* wtp = wt2 + (size_t)r * (8 * 256 * 32);
  int tid = threadIdx.x;
  int wave = tid >> 6, lane = tid & 63;
  int l15 = lane & 15, l16 = lane >> 4;
  int row0 = blockIdx.x * 64;
  f32x4 acc[4][4] = {};
  int ar = tid >> 2, ac = (tid & 3) * 16;  // 16 floats per thread per kstep
  const float* aglob = xp + (size_t)(row0 + ar) * 256 + ac;
  for (int ks = 0; ks < 4; ++ks) {
    f32x4 a0 = *(const f32x4*)(aglob + ks * 64);
    f32x4 a1 = *(const f32x4*)(aglob + ks * 64 + 4);
    f32x4 a2 = *(const f32x4*)(aglob + ks * 64 + 8);
    f32x4 a3 = *(const f32x4*)(aglob + ks * 64 + 12);
    if (ac < 32) {
      *(short8*)(&A0lds[ar][ac]) = cvt8(a0, a1);
      *(short8*)(&A0lds[ar][ac + 8]) = cvt8(a2, a3);
    } else {
      *(short8*)(&A1lds[ar][ac - 32]) = cvt8(a0, a1);
      *(short8*)(&A1lds[ar][ac - 24]) = cvt8(a2, a3);
    }
    const unsigned short* b0 = wtp + (2 * ks) * 8192;
    const unsigned short* b1 = wtp + (2 * ks + 1) * 8192;
#pragma unroll
    for (int i = 0; i < 4; ++i) {
      int cidx = tid + 256 * i;
      *(short8*)(&B0lds[cidx >> 2][(cidx & 3) * 8]) = *(const short8*)(b0 + cidx * 8);
      *(short8*)(&B1lds[cidx >> 2][(cidx & 3) * 8]) = *(const short8*)(b1 + cidx * 8);
    }
    __syncthreads();
#pragma unroll
    for (int kk = 0; kk < 2; ++kk) {
      short8 af[4], bf[4];
#pragma unroll
      for (int mt = 0; mt < 4; ++mt)
        af[mt] = kk ? *(const short8*)(&A1lds[mt * 16 + l15][l16 * 8])
                    : *(const short8*)(&A0lds[mt * 16 + l15][l16 * 8]);
#pragma unroll
      for (int nt = 0; nt < 4; ++nt)
        bf[nt] = kk ? *(const short8*)(&B1lds[wave * 64 + nt * 16 + l15][l16 * 8])
                    : *(const short8*)(&B0lds[wave * 64 + nt * 16 + l15][l16 * 8]);
#pragma unroll
      for (int mt = 0; mt < 4; ++mt)
#pragma unroll
        for (int nt = 0; nt < 4; ++nt)
          acc[mt][nt] = __builtin_amdgcn_mfma_f32_16x16x32_bf16(af[mt], bf[nt], acc[mt][nt], 0, 0, 0);
    }
    __syncthreads();
  }
#pragma unroll
  for (int mt = 0; mt < 4; ++mt)
#pragma unroll
    for (int nt = 0; nt < 4; ++nt)
#pragma unroll
      for (int rr = 0; rr < 4; ++rr) {
        int row = row0 + mt * 16 + l16 * 4 + rr;
        hbi[((size_t)(r * NN + row) * 2 + g) * 256 + wave * 64 + nt * 16 + l15] =
            f2bf(acc[mt][nt][rr]);
      }
}

// ---- one-relation aggregation for BOTH graphs, 8-edge groups --------------
__device__ __forceinline__ void agg_one2(
    int r, int d, int lane,
    const int* __restrict__ rowptr4, const int* __restrict__ adj4,
    const float* __restrict__ alpf, const unsigned short* __restrict__ hbi,
    const float* __restrict__ maxsrc, f32x4& o0, f32x4& o1) {
  const int srct[4] = {0, 1, 0, 2};
  const int dstt[4] = {1, 0, 2, 0};
  int h = lane >> 3, e8 = lane & 7, ob = lane & 56;
  const int* rowptr = rowptr4 + r * (NN + 1);
  const int* adj = adj4 + (size_t)r * EE;
  const float* asb = alpf + ((size_t)(srct[r] * 8 + 2 * r) * NN) * 16;
  const float* adb = alpf + ((size_t)(dstt[r] * 8 + 2 * r + 1) * NN) * 16;
  const unsigned short* hbr = hbi + (size_t)(r * NN) * 512;

  int beg = rowptr[d], end = rowptr[d + 1];
  float2 adp = *(const float2*)(adb + (size_t)d * 16 + h * 2);
  float adst0 = adp.x, adst1 = adp.y;
  float ub0 = lrelu(maxsrc[r * 8 + h] + adst0);       // exact segment upper bound
  float ub1 = lrelu(maxsrc[(4 + r) * 8 + h] + adst1);
  float2 asp = *(const float2*)(asb + (size_t)d * 16 + h * 2);
  float ws0 = __expf(lrelu(asp.x + adst0) - ub0);
  float ws1 = __expf(lrelu(asp.y + adst1) - ub1);
  float ssum0 = (e8 == 0) ? ws0 : 0.0f;
  float ssum1 = (e8 == 0) ? ws1 : 0.0f;
  const unsigned short* selfrow = hbr + (size_t)d * 512;
  f32x4 hv0 = ld_bf4(selfrow + lane * 4);
  f32x4 hv1 = ld_bf4(selfrow + 256 + lane * 4);
  f32x4 acc0, acc1;
#pragma unroll
  for (int i = 0; i < 4; ++i) { acc0[i] = ws0 * hv0[i]; acc1[i] = ws1 * hv1[i]; }

  for (int j0 = beg; j0 < end; j0 += 8) {
    int j = j0 + e8;
    bool valid = j < end;
    int s = valid ? adj[j] : d;
    float2 lp = *(const float2*)(asb + (size_t)s * 16 + h * 2);
    float w0 = valid ? __expf(lrelu(lp.x + adst0) - ub0) : 0.f;
    float w1 = valid ? __expf(lrelu(lp.y + adst1) - ub1) : 0.f;
    ssum0 += w0;
    ssum1 += w1;
#pragma unroll
    for (int e2 = 0; e2 < 8; ++e2) {
      int se = __shfl(s, ob + e2, 64);
      float w0e = __shfl(w0, ob + e2, 64);
      float w1e = __shfl(w1, ob + e2, 64);
      const unsigned short* row = hbr + (size_t)se * 512;
      f32x4 g0 = ld_bf4(row + lane * 4);
      f32x4 g1 = ld_bf4(row + 256 + lane * 4);
#pragma unroll
      for (int i = 0; i < 4; ++i) { acc0[i] += w0e * g0[i]; acc1[i] += w1e * g1[i]; }
    }
  }
  ssum0 += __shfl_xor(ssum0, 1, 64);
  ssum0 += __shfl_xor(ssum0, 2, 64);
  ssum0 += __shfl_xor(ssum0, 4, 64);
  ssum1 += __shfl_xor(ssum1, 1, 64);
  ssum1 += __shfl_xor(ssum1, 2, 64);
  ssum1 += __shfl_xor(ssum1, 4, 64);
  float i0 = 1.f / ssum0, i1 = 1.f / ssum1;
#pragma unroll
  for (int i = 0; i < 4; ++i) { o0[i] = acc0[i] * i0; o1[i] = acc1[i] * i1; }
}

// ---- persistent-wave aggregation, 2-wave blocks, both graphs per item -----
#define AGG_BLOCKS2 3000
__global__ __launch_bounds__(128) void k_agg7(
    const int* __restrict__ rowptr4, const int* __restrict__ adj4,
    const float* __restrict__ alpf, const unsigned short* __restrict__ hbi,
    const float* __restrict__ bias, const float* __restrict__ maxsrc,
    float* __restrict__ out) {
  int lane = threadIdx.x & 63;
  int wgid = blockIdx.x * 2 + ((int)threadIdx.x >> 6);
  const int NWV = AGG_BLOCKS2 * 2;
  for (int item = wgid; item < 3 * NN; item += NWV) {
    int y = item / NN;
    int d = item - y * NN;
    f32x4 r0g0, r0g1, r1g0, r1g1;
    int sec;
    if (y == 1) {
      agg_one2(1, d, lane, rowptr4, adj4, alpf, hbi, maxsrc, r0g0, r0g1);
      agg_one2(3, d, lane, rowptr4, adj4, alpf, hbi, maxsrc, r1g0, r1g1);
      f32x4 b1 = *(const f32x4*)(bias + 1 * 256 + lane * 4);
      f32x4 b3 = *(const f32x4*)(bias + 3 * 256 + lane * 4);
#pragma unroll
      for (int i = 0; i < 4; ++i) {
        r0g0[i] = 0.5f * (r0g0[i] + b1[i] + r1g0[i] + b3[i]);
        r0g1[i] = 0.5f * (r0g1[i] + b1[i] + r1g1[i] + b3[i]);
      }
      sec = 0;
    } else {
      int r = (y == 0) ? 0 : 2;
      agg_one2(r, d, lane, rowptr4, adj4, alpf, hbi, maxsrc, r0g0, r0g1);
      f32x4 bv = *(const f32x4*)(bias + r * 256 + lane * 4);
#pragma unroll
      for (int i = 0; i < 4; ++i) { r0g0[i] += bv[i]; r0g1[i] += bv[i]; }
      sec = (y == 0) ? 1 : 2;
    }
    f32x4* op0 = (f32x4*)(out + ((size_t)(0 + sec) * NN + d) * 256 + lane * 4);
    f32x4* op1 = (f32x4*)(out + ((size_t)(3 + sec) * NN + d) * 256 + lane * 4);
    __builtin_nontemporal_store(r0g0, op0);
    __builtin_nontemporal_store(r0g1, op1);
  }
}

extern "C" void kernel_launch(void* const* d_in, const int* in_sizes, int n_in,
                              void* d_out, int out_size, void* d_ws, size_t ws_size,
                              hipStream_t stream) {
  (void)in_sizes; (void)n_in; (void)out_size; (void)ws_size;
  const float* x[6];
  for (int i = 0; i < 6; ++i) x[i] = (const float*)d_in[i];
  const float* W = (const float*)d_in[6];
  const float* att_src = (const float*)d_in[7];
  const float* att_dst = (const float*)d_in[8];
  const float* bias = (const float*)d_in[9];
  const int* ei[4] = {(const int*)d_in[10], (const int*)d_in[11],
                      (const int*)d_in[12], (const int*)d_in[13]};
  float* out = (float*)d_out;

  char* ws = (char*)d_ws;
  size_t off = 0;
  auto take = [&](size_t bytes) -> char* {
    char* p = ws + off;
    off += (bytes + 255) & ~(size_t)255;
    return p;
  };
  unsigned short* hbi = (unsigned short*)take(8ull * NN * 256 * 2);   // 163.8 MB
  float* alpf = (float*)take(3ull * 8 * NN * 16 * 4);                 // 61.4 MB
  unsigned short* wt2 = (unsigned short*)take(4ull * 8 * 256 * 32 * 2);
  unsigned short* weffb = (unsigned short*)take(8ull * 64 * 32 * 2);
  int* cnt = (int*)take(4ull * NN * 4);
  int* rowptr = (int*)take(4ull * (NN + 1) * 4);
  int* cursor = (int*)take(4ull * NN * 4);
  int* adj = (int*)take(4ull * EE * 4);
  float* pmax = (float*)take(8ull * 32 * 8 * 4);
  float* maxsrc = (float*)take(64ull * 4);

  k_prep<<<dim3(1088), 256, 0, stream>>>(W, att_src, att_dst, wt2, weffb);
  hipMemsetAsync(cnt, 0, 4ull * NN * 4, stream);
  k_hist<<<dim3((EE + 255) / 256, 4), 256, 0, stream>>>(ei[0], ei[1], ei[2], ei[3], cnt);
  k_scan<<<dim3(4), 1024, 0, stream>>>(cnt, rowptr, cursor);
  k_scatter<<<dim3((EE + 255) / 256, 4), 256, 0, stream>>>(ei[0], ei[1], ei[2], ei[3], cursor, adj);
  k_algemm<<<dim3(625, 6), 256, 0, stream>>>(x[0], x[1], x[2], x[3], x[4], x[5],
                                             weffb, alpf);
  k_maxsrcp<<<dim3(8, 32), 256, 0, stream>>>(alpf, pmax);
  k_maxfin<<<dim3(1), 64, 0, stream>>>(pmax, maxsrc);
  k_gemmb8<<<dim3(625, 8), 256, 0, stream>>>(x[0], x[1], x[2], x[3], x[4], x[5],
                                             wt2, hbi);
  k_agg7<<<dim3(AGG_BLOCKS2), 128, 0, stream>>>(rowptr, adj, alpf, hbi, bias, maxsrc, out);
}

// Round 11
// 759.934 us; speedup vs baseline: 1.0871x; 1.0824x over previous
//
#include <hip/hip_runtime.h>

#define NN 40000
#define EE 400000

typedef short short8 __attribute__((ext_vector_type(8)));
typedef float f32x4 __attribute__((ext_vector_type(4)));
typedef unsigned short ushort4_ __attribute__((ext_vector_type(4)));

__device__ __forceinline__ unsigned short f2bf(float f) {
  unsigned int u = __float_as_uint(f);
  u = (u + 0x7FFFu + ((u >> 16) & 1u)) >> 16;
  return (unsigned short)u;
}

__device__ __forceinline__ short8 cvt8(f32x4 a, f32x4 b) {
  short8 r;
  r[0] = (short)f2bf(a[0]); r[1] = (short)f2bf(a[1]);
  r[2] = (short)f2bf(a[2]); r[3] = (short)f2bf(a[3]);
  r[4] = (short)f2bf(b[0]); r[5] = (short)f2bf(b[1]);
  r[6] = (short)f2bf(b[2]); r[7] = (short)f2bf(b[3]);
  return r;
}

__device__ __forceinline__ f32x4 ld_bf4(const unsigned short* p) {
  ushort4_ u = *(const ushort4_*)p;
  f32x4 r;
  r[0] = __uint_as_float((unsigned int)u[0] << 16);
  r[1] = __uint_as_float((unsigned int)u[1] << 16);
  r[2] = __uint_as_float((unsigned int)u[2] << 16);
  r[3] = __uint_as_float((unsigned int)u[3] << 16);
  return r;
}

__device__ __forceinline__ float lrelu(float v) { return v >= 0.f ? v : 0.2f * v; }

// ---- fused prep: wt2 (bf16 W, k-tiled) + weffb (bf16 W·att, B layout) -----
__global__ __launch_bounds__(256) void k_prep(const float* __restrict__ W,
                                              const float* __restrict__ asrc,
                                              const float* __restrict__ adst,
                                              unsigned short* __restrict__ wt2,
                                              unsigned short* __restrict__ weffb) {
  int idx = blockIdx.x * 256 + threadIdx.x;
  if (idx < 262144) {
    int k0 = idx & 31, n = (idx >> 5) & 255, kt = (idx >> 13) & 7, r = idx >> 16;
    wt2[idx] = f2bf(W[((size_t)(r * 256) + (kt * 32 + k0)) * 256 + n]);
  } else if (idx < 262144 + 16384) {
    int id2 = idx - 262144;
    int k0 = id2 & 31, col = (id2 >> 5) & 63, kt = id2 >> 11;
    int q = col >> 3, j = col & 7;
    int r = q >> 1, side = q & 1;
    int f = kt * 32 + k0;
    const float* att = side ? adst : asrc;
    const float* wrow = W + ((size_t)(r * 256) + f) * 256 + j * 32;
    const float* arow = att + (r * 8 + j) * 32;
    float s = 0.f;
#pragma unroll
    for (int c = 0; c < 32; ++c) s += wrow[c] * arow[c];
    weffb[id2] = f2bf(s);
  }
}

// ---- CSR build ------------------------------------------------------------
__global__ __launch_bounds__(256) void k_hist(
    const int* __restrict__ e0, const int* __restrict__ e1,
    const int* __restrict__ e2, const int* __restrict__ e3, int* __restrict__ cnt) {
  int r = blockIdx.y;
  const int* ei = (r == 0) ? e0 : (r == 1) ? e1 : (r == 2) ? e2 : e3;
  int e = blockIdx.x * 256 + threadIdx.x;
  if (e < EE) atomicAdd(&cnt[r * NN + ei[EE + e]], 1);
}

__global__ __launch_bounds__(1024) void k_scan(const int* __restrict__ cnt,
                                               int* __restrict__ rowptr,
                                               int* __restrict__ cursor) {
  int r = blockIdx.x;
  const int* c = cnt + r * NN;
  int* rp = rowptr + r * (NN + 1);
  int* cur = cursor + r * NN;
  __shared__ int part[1024];
  int t = threadIdx.x;
  const int per = 40;  // 1024*40 >= 40000
  int base = t * per;
  int sum = 0;
  for (int i = 0; i < per; ++i) { int idx = base + i; if (idx < NN) sum += c[idx]; }
  part[t] = sum;
  __syncthreads();
  for (int o = 1; o < 1024; o <<= 1) {
    int v = (t >= o) ? part[t - o] : 0;
    __syncthreads();
    part[t] += v;
    __syncthreads();
  }
  int run = part[t] - sum;  // exclusive prefix
  for (int i = 0; i < per; ++i) {
    int idx = base + i;
    if (idx < NN) { rp[idx] = run; cur[idx] = run; run += c[idx]; }
  }
  if (t == 1023) rp[NN] = part[1023];
}

__global__ __launch_bounds__(256) void k_scatter(
    const int* __restrict__ e0, const int* __restrict__ e1,
    const int* __restrict__ e2, const int* __restrict__ e3,
    int* __restrict__ cursor, int* __restrict__ adj) {
  int r = blockIdx.y;
  const int* ei = (r == 0) ? e0 : (r == 1) ? e1 : (r == 2) ? e2 : e3;
  int e = blockIdx.x * 256 + threadIdx.x;
  if (e < EE) {
    int s = ei[e], d = ei[EE + e];
    int pos = atomicAdd(&cursor[r * NN + d], 1);
    adj[(size_t)r * EE + pos] = s;
  }
}

// ---- fused GEMM: hbi[r][n][g][256] = bf16(x @ W), BK=64 -------------------
// plus (r != 2): alpf[t][q][n][h][g] = x @ weffb  (t = srct[r], logits)
__global__ __launch_bounds__(256) void k_gemmb8(
    const float* __restrict__ x0, const float* __restrict__ x1, const float* __restrict__ x2,
    const float* __restrict__ x3, const float* __restrict__ x4, const float* __restrict__ x5,
    const unsigned short* __restrict__ wt2, const unsigned short* __restrict__ weffb,
    unsigned short* __restrict__ hbi, float* __restrict__ alpf) {
  __shared__ __attribute__((aligned(16))) unsigned short A0lds[64][40];
  __shared__ __attribute__((aligned(16))) unsigned short A1lds[64][40];
  __shared__ __attribute__((aligned(16))) unsigned short B0lds[256][40];
  __shared__ __attribute__((aligned(16))) unsigned short B1lds[256][40];
  const int srct[4] = {0, 1, 0, 2};
  int y = blockIdx.y;  // g*4 + r
  int g = y >> 2, r = y & 3;
  int ty = srct[r];
  int t6 = g * 3 + ty;
  const float* xp;
  switch (t6) { case 0: xp = x0; break; case 1: xp = x1; break; case 2: xp = x2; break;
                case 3: xp = x3; break; case 4: xp = x4; break; default: xp = x5; break; }
  const unsigned short* wtp = wt2 + (size_t)r * (8 * 256 * 32);
  int tid = threadIdx.x;
  int wave = tid >> 6, lane = tid & 63;
  int l15 = lane & 15, l16 = lane >> 4;
  int row0 = blockIdx.x * 64;
  f32x4 acc[4][4] = {};
  f32x4 lacc[4] = {};
  bool dolog = (r != 2);
  int lcol = wave * 16 + l15;
  int ar = tid >> 2, ac = (tid & 3) * 16;  // 16 floats per thread per kstep
  const float* aglob = xp + (size_t)(row0 + ar) * 256 + ac;
  for (int ks = 0; ks < 4; ++ks) {
    f32x4 a0 = *(const f32x4*)(aglob + ks * 64);
    f32x4 a1 = *(const f32x4*)(aglob + ks * 64 + 4);
    f32x4 a2 = *(const f32x4*)(aglob + ks * 64 + 8);
    f32x4 a3 = *(const f32x4*)(aglob + ks * 64 + 12);
    if (ac < 32) {
      *(short8*)(&A0lds[ar][ac]) = cvt8(a0, a1);
      *(short8*)(&A0lds[ar][ac + 8]) = cvt8(a2, a3);
    } else {
      *(short8*)(&A1lds[ar][ac - 32]) = cvt8(a0, a1);
      *(short8*)(&A1lds[ar][ac - 24]) = cvt8(a2, a3);
    }
    const unsigned short* b0 = wtp + (2 * ks) * 8192;
    const unsigned short* b1 = wtp + (2 * ks + 1) * 8192;
#pragma unroll
    for (int i = 0; i < 4; ++i) {
      int cidx = tid + 256 * i;
      *(short8*)(&B0lds[cidx >> 2][(cidx & 3) * 8]) = *(const short8*)(b0 + cidx * 8);
      *(short8*)(&B1lds[cidx >> 2][(cidx & 3) * 8]) = *(const short8*)(b1 + cidx * 8);
    }
    __syncthreads();
#pragma unroll
    for (int kk = 0; kk < 2; ++kk) {
      short8 af[4], bf[4];
#pragma unroll
      for (int mt = 0; mt < 4; ++mt)
        af[mt] = kk ? *(const short8*)(&A1lds[mt * 16 + l15][l16 * 8])
                    : *(const short8*)(&A0lds[mt * 16 + l15][l16 * 8]);
#pragma unroll
      for (int nt = 0; nt < 4; ++nt)
        bf[nt] = kk ? *(const short8*)(&B1lds[wave * 64 + nt * 16 + l15][l16 * 8])
                    : *(const short8*)(&B0lds[wave * 64 + nt * 16 + l15][l16 * 8]);
#pragma unroll
      for (int mt = 0; mt < 4; ++mt)
#pragma unroll
        for (int nt = 0; nt < 4; ++nt)
          acc[mt][nt] = __builtin_amdgcn_mfma_f32_16x16x32_bf16(af[mt], bf[nt], acc[mt][nt], 0, 0, 0);
      if (dolog) {
        short8 lb = *(const short8*)(weffb + (2 * ks + kk) * 2048 + lcol * 32 + l16 * 8);
#pragma unroll
        for (int mt = 0; mt < 4; ++mt)
          lacc[mt] = __builtin_amdgcn_mfma_f32_16x16x32_bf16(af[mt], lb, lacc[mt], 0, 0, 0);
      }
    }
    __syncthreads();
  }
#pragma unroll
  for (int mt = 0; mt < 4; ++mt)
#pragma unroll
    for (int nt = 0; nt < 4; ++nt)
#pragma unroll
      for (int rr = 0; rr < 4; ++rr) {
        int row = row0 + mt * 16 + l16 * 4 + rr;
        hbi[((size_t)(r * NN + row) * 2 + g) * 256 + wave * 64 + nt * 16 + l15] =
            f2bf(acc[mt][nt][rr]);
      }
  if (dolog) {
    int q = lcol >> 3, jj = lcol & 7;
#pragma unroll
    for (int mt = 0; mt < 4; ++mt)
#pragma unroll
      for (int rr = 0; rr < 4; ++rr) {
        int row = row0 + mt * 16 + l16 * 4 + rr;
        alpf[((size_t)(ty * 8 + q) * NN + row) * 16 + jj * 2 + g] = lacc[mt][rr];
      }
  }
}

// ---- per-head global max of alsrc column ----------------------------------
__global__ __launch_bounds__(256) void k_maxsrcp(const float* __restrict__ alpf,
                                                 float* __restrict__ pmax) {
  const int srct[4] = {0, 1, 0, 2};
  int gr = blockIdx.x, slice = blockIdx.y;
  int g = gr >> 2, r = gr & 3;
  const float* col = alpf + ((size_t)(srct[r] * 8 + 2 * r) * NN) * 16;
  int t = threadIdx.x;
  int h = t & 7, chunk = t >> 3;  // 32 chunks
  float m = -1e30f;
  for (int nn = chunk; nn < 1250; nn += 32)
    m = fmaxf(m, col[(size_t)(slice * 1250 + nn) * 16 + h * 2 + g]);
  __shared__ float red[256];
  red[t] = m;
  __syncthreads();
  for (int o = 128; o >= 8; o >>= 1) {
    if (t < o) red[t] = fmaxf(red[t], red[t + o]);
    __syncthreads();
  }
  if (t < 8) pmax[(gr * 32 + slice) * 8 + t] = red[t];
}

__global__ __launch_bounds__(64) void k_maxfin(const float* __restrict__ pmax,
                                               float* __restrict__ maxsrc) {
  int t = threadIdx.x;  // 64 = 8 gr * 8 h
  int gr = t >> 3, h = t & 7;
  float m = -1e30f;
  for (int s = 0; s < 32; ++s) m = fmaxf(m, pmax[(gr * 32 + s) * 8 + h]);
  maxsrc[t] = m;
}

// ---- one-relation aggregation for BOTH graphs, 8-edge groups --------------
__device__ __forceinline__ void agg_one2(
    int r, int d, int lane,
    const int* __restrict__ rowptr4, const int* __restrict__ adj4,
    const float* __restrict__ alpf, const unsigned short* __restrict__ hbi,
    const float* __restrict__ maxsrc, f32x4& o0, f32x4& o1) {
  const int srct[4] = {0, 1, 0, 2};
  const int dstt[4] = {1, 0, 2, 0};
  int h = lane >> 3, e8 = lane & 7, ob = lane & 56;
  const int* rowptr = rowptr4 + r * (NN + 1);
  const int* adj = adj4 + (size_t)r * EE;
  const float* asb = alpf + ((size_t)(srct[r] * 8 + 2 * r) * NN) * 16;
  const float* adb = alpf + ((size_t)(dstt[r] * 8 + 2 * r + 1) * NN) * 16;
  const unsigned short* hbr = hbi + (size_t)(r * NN) * 512;

  int beg = rowptr[d], end = rowptr[d + 1];
  float2 adp = *(const float2*)(adb + (size_t)d * 16 + h * 2);
  float adst0 = adp.x, adst1 = adp.y;
  float ub0 = lrelu(maxsrc[r * 8 + h] + adst0);       // exact segment upper bound
  float ub1 = lrelu(maxsrc[(4 + r) * 8 + h] + adst1);
  float2 asp = *(const float2*)(asb + (size_t)d * 16 + h * 2);
  float ws0 = __expf(lrelu(asp.x + adst0) - ub0);
  float ws1 = __expf(lrelu(asp.y + adst1) - ub1);
  float ssum0 = (e8 == 0) ? ws0 : 0.0f;
  float ssum1 = (e8 == 0) ? ws1 : 0.0f;
  const unsigned short* selfrow = hbr + (size_t)d * 512;
  f32x4 hv0 = ld_bf4(selfrow + lane * 4);
  f32x4 hv1 = ld_bf4(selfrow + 256 + lane * 4);
  f32x4 acc0, acc1;
#pragma unroll
  for (int i = 0; i < 4; ++i) { acc0[i] = ws0 * hv0[i]; acc1[i] = ws1 * hv1[i]; }

  for (int j0 = beg; j0 < end; j0 += 8) {
    int j = j0 + e8;
    bool valid = j < end;
    int s = valid ? adj[j] : d;
    float2 lp = *(const float2*)(asb + (size_t)s * 16 + h * 2);
    float w0 = valid ? __expf(lrelu(lp.x + adst0) - ub0) : 0.f;
    float w1 = valid ? __expf(lrelu(lp.y + adst1) - ub1) : 0.f;
    ssum0 += w0;
    ssum1 += w1;
#pragma unroll
    for (int e2 = 0; e2 < 8; ++e2) {
      int se = __shfl(s, ob + e2, 64);
      float w0e = __shfl(w0, ob + e2, 64);
      float w1e = __shfl(w1, ob + e2, 64);
      const unsigned short* row = hbr + (size_t)se * 512;
      f32x4 g0 = ld_bf4(row + lane * 4);
      f32x4 g1 = ld_bf4(row + 256 + lane * 4);
#pragma unroll
      for (int i = 0; i < 4; ++i) { acc0[i] += w0e * g0[i]; acc1[i] += w1e * g1[i]; }
    }
  }
  ssum0 += __shfl_xor(ssum0, 1, 64);
  ssum0 += __shfl_xor(ssum0, 2, 64);
  ssum0 += __shfl_xor(ssum0, 4, 64);
  ssum1 += __shfl_xor(ssum1, 1, 64);
  ssum1 += __shfl_xor(ssum1, 2, 64);
  ssum1 += __shfl_xor(ssum1, 4, 64);
  float i0 = 1.f / ssum0, i1 = 1.f / ssum1;
#pragma unroll
  for (int i = 0; i < 4; ++i) { o0[i] = acc0[i] * i0; o1[i] = acc1[i] * i1; }
}

// ---- persistent-wave aggregation, both graphs per item --------------------
#define AGG_BLOCKS 1875
__global__ __launch_bounds__(256) void k_agg6(
    const int* __restrict__ rowptr4, const int* __restrict__ adj4,
    const float* __restrict__ alpf, const unsigned short* __restrict__ hbi,
    const float* __restrict__ bias, const float* __restrict__ maxsrc,
    float* __restrict__ out) {
  int lane = threadIdx.x & 63;
  int wgid = (blockIdx.x * 256 + (int)threadIdx.x) >> 6;
  const int NWV = AGG_BLOCKS * 4;
  for (int item = wgid; item < 3 * NN; item += NWV) {
    int y = item / NN;
    int d = item - y * NN;
    f32x4 r0g0, r0g1, r1g0, r1g1;
    int sec;
    if (y == 1) {
      agg_one2(1, d, lane, rowptr4, adj4, alpf, hbi, maxsrc, r0g0, r0g1);
      agg_one2(3, d, lane, rowptr4, adj4, alpf, hbi, maxsrc, r1g0, r1g1);
      f32x4 b1 = *(const f32x4*)(bias + 1 * 256 + lane * 4);
      f32x4 b3 = *(const f32x4*)(bias + 3 * 256 + lane * 4);
#pragma unroll
      for (int i = 0; i < 4; ++i) {
        r0g0[i] = 0.5f * (r0g0[i] + b1[i] + r1g0[i] + b3[i]);
        r0g1[i] = 0.5f * (r0g1[i] + b1[i] + r1g1[i] + b3[i]);
      }
      sec = 0;
    } else {
      int r = (y == 0) ? 0 : 2;
      agg_one2(r, d, lane, rowptr4, adj4, alpf, hbi, maxsrc, r0g0, r0g1);
      f32x4 bv = *(const f32x4*)(bias + r * 256 + lane * 4);
#pragma unroll
      for (int i = 0; i < 4; ++i) { r0g0[i] += bv[i]; r0g1[i] += bv[i]; }
      sec = (y == 0) ? 1 : 2;
    }
    f32x4* op0 = (f32x4*)(out + ((size_t)(0 + sec) * NN + d) * 256 + lane * 4);
    f32x4* op1 = (f32x4*)(out + ((size_t)(3 + sec) * NN + d) * 256 + lane * 4);
    __builtin_nontemporal_store(r0g0, op0);
    __builtin_nontemporal_store(r0g1, op1);
  }
}

extern "C" void kernel_launch(void* const* d_in, const int* in_sizes, int n_in,
                              void* d_out, int out_size, void* d_ws, size_t ws_size,
                              hipStream_t stream) {
  (void)in_sizes; (void)n_in; (void)out_size; (void)ws_size;
  const float* x[6];
  for (int i = 0; i < 6; ++i) x[i] = (const float*)d_in[i];
  const float* W = (const float*)d_in[6];
  const float* att_src = (const float*)d_in[7];
  const float* att_dst = (const float*)d_in[8];
  const float* bias = (const float*)d_in[9];
  const int* ei[4] = {(const int*)d_in[10], (const int*)d_in[11],
                      (const int*)d_in[12], (const int*)d_in[13]};
  float* out = (float*)d_out;

  char* ws = (char*)d_ws;
  size_t off = 0;
  auto take = [&](size_t bytes) -> char* {
    char* p = ws + off;
    off += (bytes + 255) & ~(size_t)255;
    return p;
  };
  unsigned short* hbi = (unsigned short*)take(8ull * NN * 256 * 2);   // 163.8 MB
  float* alpf = (float*)take(3ull * 8 * NN * 16 * 4);                 // 61.4 MB
  unsigned short* wt2 = (unsigned short*)take(4ull * 8 * 256 * 32 * 2);
  unsigned short* weffb = (unsigned short*)take(8ull * 64 * 32 * 2);
  int* cnt = (int*)take(4ull * NN * 4);
  int* rowptr = (int*)take(4ull * (NN + 1) * 4);
  int* cursor = (int*)take(4ull * NN * 4);
  int* adj = (int*)take(4ull * EE * 4);
  float* pmax = (float*)take(8ull * 32 * 8 * 4);
  float* maxsrc = (float*)take(64ull * 4);

  k_prep<<<dim3(1088), 256, 0, stream>>>(W, att_src, att_dst, wt2, weffb);
  hipMemsetAsync(cnt, 0, 4ull * NN * 4, stream);
  k_hist<<<dim3((EE + 255) / 256, 4), 256, 0, stream>>>(ei[0], ei[1], ei[2], ei[3], cnt);
  k_scan<<<dim3(4), 1024, 0, stream>>>(cnt, rowptr, cursor);
  k_scatter<<<dim3((EE + 255) / 256, 4), 256, 0, stream>>>(ei[0], ei[1], ei[2], ei[3], cursor, adj);
  k_gemmb8<<<dim3(625, 8), 256, 0, stream>>>(x[0], x[1], x[2], x[3], x[4], x[5],
                                             wt2, weffb, hbi, alpf);
  k_maxsrcp<<<dim3(8, 32), 256, 0, stream>>>(alpf, pmax);
  k_maxfin<<<dim3(1), 64, 0, stream>>>(pmax, maxsrc);
  k_agg6<<<dim3(AGG_BLOCKS), 256, 0, stream>>>(rowptr, adj, alpf, hbi, bias, maxsrc, out);
}

// Round 13
// 755.276 us; speedup vs baseline: 1.0939x; 1.0062x over previous
//
#include <hip/hip_runtime.h>
#include <hip/hip_bf16.h>

#define NN 40000
#define EE 400000

typedef short short8 __attribute__((ext_vector_type(8)));
typedef float f32x4 __attribute__((ext_vector_type(4)));
typedef unsigned short ushort4_ __attribute__((ext_vector_type(4)));
typedef unsigned int uint4_ __attribute__((ext_vector_type(4)));

__device__ __forceinline__ unsigned short f2bf(float f) {
  unsigned int u = __float_as_uint(f);
  u = (u + 0x7FFFu + ((u >> 16) & 1u)) >> 16;
  return (unsigned short)u;
}

// packed f32->bf16 (RNE) — compiler emits v_cvt_pk_bf16_f32
__device__ __forceinline__ unsigned cvtpk(float lo, float hi) {
  __hip_bfloat162 t = __float22bfloat162_rn(float2{lo, hi});
  return *reinterpret_cast<unsigned*>(&t);
}

__device__ __forceinline__ short8 cvt8(f32x4 a, f32x4 b) {
  uint4_ u;
  u[0] = cvtpk(a[0], a[1]);
  u[1] = cvtpk(a[2], a[3]);
  u[2] = cvtpk(b[0], b[1]);
  u[3] = cvtpk(b[2], b[3]);
  return *reinterpret_cast<short8*>(&u);
}

__device__ __forceinline__ f32x4 ld_bf4(const unsigned short* p) {
  ushort4_ u = *(const ushort4_*)p;
  f32x4 r;
  r[0] = __uint_as_float((unsigned int)u[0] << 16);
  r[1] = __uint_as_float((unsigned int)u[1] << 16);
  r[2] = __uint_as_float((unsigned int)u[2] << 16);
  r[3] = __uint_as_float((unsigned int)u[3] << 16);
  return r;
}

__device__ __forceinline__ float lrelu(float v) { return v >= 0.f ? v : 0.2f * v; }

// monotone float<->uint encoding for atomicMax on floats
__device__ __forceinline__ unsigned fenc(float f) {
  unsigned b = __float_as_uint(f);
  return (b & 0x80000000u) ? ~b : (b | 0x80000000u);
}
__device__ __forceinline__ float fdec(unsigned e) {
  return __uint_as_float((e >> 31) ? (e & 0x7fffffffu) : ~e);
}

// ---- fused prep: wt2 (bf16 W, k-tiled, chunk-swizzled) + weffb + zeroing --
// wt2 tile layout: [n][c'*8+e] holds W[kt*32 + (c'^((n>>1)&3))*8 + e][n]
// so linear global_load_lds staging yields the bank-swizzled LDS image.
__global__ __launch_bounds__(256) void k_prep(const float* __restrict__ W,
                                              const float* __restrict__ asrc,
                                              const float* __restrict__ adst,
                                              unsigned short* __restrict__ wt2,
                                              unsigned short* __restrict__ weffb,
                                              int* __restrict__ cnt,
                                              unsigned* __restrict__ maxsrcE) {
  int idx = blockIdx.x * 256 + threadIdx.x;
  if (idx < 262144) {
    int k0 = idx & 31, n = (idx >> 5) & 255, kt = (idx >> 13) & 7, r = idx >> 16;
    int cp = k0 >> 3, e = k0 & 7;
    int k0s = ((cp ^ ((n >> 1) & 3)) << 3) | e;
    wt2[idx] = f2bf(W[((size_t)(r * 256) + (kt * 32 + k0s)) * 256 + n]);
  } else if (idx < 262144 + 16384) {
    int id2 = idx - 262144;
    int k0 = id2 & 31, col = (id2 >> 5) & 63, kt = id2 >> 11;
    int q = col >> 3, j = col & 7;
    int r = q >> 1, side = q & 1;
    int f = kt * 32 + k0;
    const float* att = side ? adst : asrc;
    const float* wrow = W + ((size_t)(r * 256) + f) * 256 + j * 32;
    const float* arow = att + (r * 8 + j) * 32;
    float s = 0.f;
#pragma unroll
    for (int c = 0; c < 32; ++c) s += wrow[c] * arow[c];
    weffb[id2] = f2bf(s);
  } else if (idx < 262144 + 16384 + 160000) {
    cnt[idx - (262144 + 16384)] = 0;
  } else if (idx < 262144 + 16384 + 160000 + 64) {
    maxsrcE[idx - (262144 + 16384 + 160000)] = 0u;
  }
}

// ---- CSR build ------------------------------------------------------------
__global__ __launch_bounds__(256) void k_hist(
    const int* __restrict__ e0, const int* __restrict__ e1,
    const int* __restrict__ e2, const int* __restrict__ e3, int* __restrict__ cnt) {
  int r = blockIdx.y;
  const int* ei = (r == 0) ? e0 : (r == 1) ? e1 : (r == 2) ? e2 : e3;
  int e = blockIdx.x * 256 + threadIdx.x;
  if (e < EE) atomicAdd(&cnt[r * NN + ei[EE + e]], 1);
}

__global__ __launch_bounds__(1024) void k_scan(const int* __restrict__ cnt,
                                               int* __restrict__ rowptr,
                                               int* __restrict__ cursor) {
  int r = blockIdx.x;
  const int* c = cnt + r * NN;
  int* rp = rowptr + r * (NN + 1);
  int* cur = cursor + r * NN;
  __shared__ int part[1024];
  int t = threadIdx.x;
  const int per = 40;  // 1024*40 >= 40000
  int base = t * per;
  int sum = 0;
  for (int i = 0; i < per; ++i) { int idx = base + i; if (idx < NN) sum += c[idx]; }
  part[t] = sum;
  __syncthreads();
  for (int o = 1; o < 1024; o <<= 1) {
    int v = (t >= o) ? part[t - o] : 0;
    __syncthreads();
    part[t] += v;
    __syncthreads();
  }
  int run = part[t] - sum;  // exclusive prefix
  for (int i = 0; i < per; ++i) {
    int idx = base + i;
    if (idx < NN) { rp[idx] = run; cur[idx] = run; run += c[idx]; }
  }
  if (t == 1023) rp[NN] = part[1023];
}

__global__ __launch_bounds__(256) void k_scatter(
    const int* __restrict__ e0, const int* __restrict__ e1,
    const int* __restrict__ e2, const int* __restrict__ e3,
    int* __restrict__ cursor, int* __restrict__ adj) {
  int r = blockIdx.y;
  const int* ei = (r == 0) ? e0 : (r == 1) ? e1 : (r == 2) ? e2 : e3;
  int e = blockIdx.x * 256 + threadIdx.x;
  if (e < EE) {
    int s = ei[e], d = ei[EE + e];
    int pos = atomicAdd(&cursor[r * NN + d], 1);
    adj[(size_t)r * EE + pos] = s;
  }
}

// ---- fused GEMM: hbi[r][n][g][256] = bf16(x @ W), BK=64 -------------------
// plus (r != 2): alpf[t][q][n][h][g] logits and maxsrcE atomic column maxes
__global__ __launch_bounds__(256) void k_gemmb8(
    const float* __restrict__ x0, const float* __restrict__ x1, const float* __restrict__ x2,
    const float* __restrict__ x3, const float* __restrict__ x4, const float* __restrict__ x5,
    const unsigned short* __restrict__ wt2, const unsigned short* __restrict__ weffb,
    unsigned short* __restrict__ hbi, float* __restrict__ alpf,
    unsigned* __restrict__ maxsrcE) {
  __shared__ __attribute__((aligned(16))) unsigned short A0lds[64][40];
  __shared__ __attribute__((aligned(16))) unsigned short A1lds[64][40];
  __shared__ __attribute__((aligned(16))) unsigned short B0lds[256][32];
  __shared__ __attribute__((aligned(16))) unsigned short B1lds[256][32];
  const int srct[4] = {0, 1, 0, 2};
  int y = blockIdx.y;  // g*4 + r
  int g = y >> 2, r = y & 3;
  int ty = srct[r];
  int t6 = g * 3 + ty;
  const float* xp;
  switch (t6) { case 0: xp = x0; break; case 1: xp = x1; break; case 2: xp = x2; break;
                case 3: xp = x3; break; case 4: xp = x4; break; default: xp = x5; break; }
  const unsigned short* wtp = wt2 + (size_t)r * (8 * 256 * 32);
  int tid = threadIdx.x;
  int wave = tid >> 6, lane = tid & 63;
  int l15 = lane & 15, l16 = lane >> 4;
  int row0 = blockIdx.x * 64;
  f32x4 acc[4][4] = {};
  f32x4 lacc[4] = {};
  bool dolog = (r != 2);
  int lcol = wave * 16 + l15;
  int ar = tid >> 2, ac = (tid & 3) * 16;  // 16 floats per thread per kstep
  const float* aglob = xp + (size_t)(row0 + ar) * 256 + ac;
  unsigned short* l0b = &B0lds[0][0];
  unsigned short* l1b = &B1lds[0][0];
  for (int ks = 0; ks < 4; ++ks) {
    // ---- B staging: direct global->LDS (wt2 pre-swizzled, LDS linear) ----
    const unsigned short* b0 = wtp + (2 * ks) * 8192;
    const unsigned short* b1 = wtp + (2 * ks + 1) * 8192;
#pragma unroll
    for (int i = 0; i < 4; ++i) {
      int gofs = (tid + 256 * i) * 8;             // per-lane source element
      int lofs = (wave * 64 + i * 256) * 8;       // wave-uniform LDS base
      __builtin_amdgcn_global_load_lds(
          (const __attribute__((address_space(1))) void*)(b0 + gofs),
          (__attribute__((address_space(3))) void*)(l0b + lofs), 16, 0, 0);
      __builtin_amdgcn_global_load_lds(
          (const __attribute__((address_space(1))) void*)(b1 + gofs),
          (__attribute__((address_space(3))) void*)(l1b + lofs), 16, 0, 0);
    }
    // ---- A staging: f32 read + packed cvt + ds_write ----
    f32x4 a0 = *(const f32x4*)(aglob + ks * 64);
    f32x4 a1 = *(const f32x4*)(aglob + ks * 64 + 4);
    f32x4 a2 = *(const f32x4*)(aglob + ks * 64 + 8);
    f32x4 a3 = *(const f32x4*)(aglob + ks * 64 + 12);
    if (ac < 32) {
      *(short8*)(&A0lds[ar][ac]) = cvt8(a0, a1);
      *(short8*)(&A0lds[ar][ac + 8]) = cvt8(a2, a3);
    } else {
      *(short8*)(&A1lds[ar][ac - 32]) = cvt8(a0, a1);
      *(short8*)(&A1lds[ar][ac - 24]) = cvt8(a2, a3);
    }
    __syncthreads();
#pragma unroll
    for (int kk = 0; kk < 2; ++kk) {
      short8 af[4], bf[4];
#pragma unroll
      for (int mt = 0; mt < 4; ++mt)
        af[mt] = kk ? *(const short8*)(&A1lds[mt * 16 + l15][l16 * 8])
                    : *(const short8*)(&A0lds[mt * 16 + l15][l16 * 8]);
#pragma unroll
      for (int nt = 0; nt < 4; ++nt) {
        int sn = wave * 64 + nt * 16 + l15;
        int cs = (l16 ^ ((sn >> 1) & 3)) * 8;     // bank swizzle (matches wt2)
        bf[nt] = kk ? *(const short8*)(&B1lds[sn][cs])
                    : *(const short8*)(&B0lds[sn][cs]);
      }
#pragma unroll
      for (int mt = 0; mt < 4; ++mt)
#pragma unroll
        for (int nt = 0; nt < 4; ++nt)
          acc[mt][nt] = __builtin_amdgcn_mfma_f32_16x16x32_bf16(af[mt], bf[nt], acc[mt][nt], 0, 0, 0);
      if (dolog) {
        short8 lb = *(const short8*)(weffb + (2 * ks + kk) * 2048 + lcol * 32 + l16 * 8);
#pragma unroll
        for (int mt = 0; mt < 4; ++mt)
          lacc[mt] = __builtin_amdgcn_mfma_f32_16x16x32_bf16(af[mt], lb, lacc[mt], 0, 0, 0);
      }
    }
    __syncthreads();
  }
#pragma unroll
  for (int mt = 0; mt < 4; ++mt)
#pragma unroll
    for (int nt = 0; nt < 4; ++nt)
#pragma unroll
      for (int rr = 0; rr < 4; ++rr) {
        int row = row0 + mt * 16 + l16 * 4 + rr;
        hbi[((size_t)(r * NN + row) * 2 + g) * 256 + wave * 64 + nt * 16 + l15] =
            f2bf(acc[mt][nt][rr]);
      }
  if (dolog) {
    int q = lcol >> 3, jj = lcol & 7;
#pragma unroll
    for (int mt = 0; mt < 4; ++mt)
#pragma unroll
      for (int rr = 0; rr < 4; ++rr) {
        int row = row0 + mt * 16 + l16 * 4 + rr;
        alpf[((size_t)(ty * 8 + q) * NN + row) * 16 + jj * 2 + g] = lacc[mt][rr];
      }
    // fused per-column max for src columns (q even, srct[q/2]==ty)
    if ((q & 1) == 0 && srct[q >> 1] == ty) {
      float m = -1e30f;
#pragma unroll
      for (int mt = 0; mt < 4; ++mt)
#pragma unroll
        for (int rr = 0; rr < 4; ++rr) m = fmaxf(m, lacc[mt][rr]);
      m = fmaxf(m, __shfl_xor(m, 16, 64));
      m = fmaxf(m, __shfl_xor(m, 32, 64));
      if (l16 == 0) atomicMax(maxsrcE + (g * 4 + (q >> 1)) * 8 + jj, fenc(m));
    }
  }
}

// ---- one-relation aggregation for BOTH graphs, 8-edge groups --------------
__device__ __forceinline__ void agg_one2(
    int r, int d, int lane,
    const int* __restrict__ rowptr4, const int* __restrict__ adj4,
    const float* __restrict__ alpf, const unsigned short* __restrict__ hbi,
    const unsigned* __restrict__ maxsrcE, f32x4& o0, f32x4& o1) {
  const int srct[4] = {0, 1, 0, 2};
  const int dstt[4] = {1, 0, 2, 0};
  int h = lane >> 3, e8 = lane & 7, ob = lane & 56;
  const int* rowptr = rowptr4 + r * (NN + 1);
  const int* adj = adj4 + (size_t)r * EE;
  const float* asb = alpf + ((size_t)(srct[r] * 8 + 2 * r) * NN) * 16;
  const float* adb = alpf + ((size_t)(dstt[r] * 8 + 2 * r + 1) * NN) * 16;
  const unsigned short* hbr = hbi + (size_t)(r * NN) * 512;

  int beg = rowptr[d], end = rowptr[d + 1];
  float2 adp = *(const float2*)(adb + (size_t)d * 16 + h * 2);
  float adst0 = adp.x, adst1 = adp.y;
  float ub0 = lrelu(fdec(maxsrcE[r * 8 + h]) + adst0);   // exact segment ub
  float ub1 = lrelu(fdec(maxsrcE[(4 + r) * 8 + h]) + adst1);
  float2 asp = *(const float2*)(asb + (size_t)d * 16 + h * 2);
  float ws0 = __expf(lrelu(asp.x + adst0) - ub0);
  float ws1 = __expf(lrelu(asp.y + adst1) - ub1);
  float ssum0 = (e8 == 0) ? ws0 : 0.0f;
  float ssum1 = (e8 == 0) ? ws1 : 0.0f;
  const unsigned short* selfrow = hbr + (size_t)d * 512;
  f32x4 hv0 = ld_bf4(selfrow + lane * 4);
  f32x4 hv1 = ld_bf4(selfrow + 256 + lane * 4);
  f32x4 acc0, acc1;
#pragma unroll
  for (int i = 0; i < 4; ++i) { acc0[i] = ws0 * hv0[i]; acc1[i] = ws1 * hv1[i]; }

  for (int j0 = beg; j0 < end; j0 += 8) {
    int j = j0 + e8;
    bool valid = j < end;
    int s = valid ? adj[j] : d;
    float2 lp = *(const float2*)(asb + (size_t)s * 16 + h * 2);
    float w0 = valid ? __expf(lrelu(lp.x + adst0) - ub0) : 0.f;
    float w1 = valid ? __expf(lrelu(lp.y + adst1) - ub1) : 0.f;
    ssum0 += w0;
    ssum1 += w1;
#pragma unroll
    for (int e2 = 0; e2 < 8; ++e2) {
      int se = __shfl(s, ob + e2, 64);
      float w0e = __shfl(w0, ob + e2, 64);
      float w1e = __shfl(w1, ob + e2, 64);
      const unsigned short* row = hbr + (size_t)se * 512;
      f32x4 g0 = ld_bf4(row + lane * 4);
      f32x4 g1 = ld_bf4(row + 256 + lane * 4);
#pragma unroll
      for (int i = 0; i < 4; ++i) { acc0[i] += w0e * g0[i]; acc1[i] += w1e * g1[i]; }
    }
  }
  ssum0 += __shfl_xor(ssum0, 1, 64);
  ssum0 += __shfl_xor(ssum0, 2, 64);
  ssum0 += __shfl_xor(ssum0, 4, 64);
  ssum1 += __shfl_xor(ssum1, 1, 64);
  ssum1 += __shfl_xor(ssum1, 2, 64);
  ssum1 += __shfl_xor(ssum1, 4, 64);
  float i0 = 1.f / ssum0, i1 = 1.f / ssum1;
#pragma unroll
  for (int i = 0; i < 4; ++i) { o0[i] = acc0[i] * i0; o1[i] = acc1[i] * i1; }
}

// ---- persistent-wave aggregation, both graphs per item --------------------
#define AGG_BLOCKS 1875
__global__ __launch_bounds__(256) void k_agg6(
    const int* __restrict__ rowptr4, const int* __restrict__ adj4,
    const float* __restrict__ alpf, const unsigned short* __restrict__ hbi,
    const float* __restrict__ bias, const unsigned* __restrict__ maxsrcE,
    float* __restrict__ out) {
  int lane = threadIdx.x & 63;
  int wgid = (blockIdx.x * 256 + (int)threadIdx.x) >> 6;
  const int NWV = AGG_BLOCKS * 4;
  for (int item = wgid; item < 3 * NN; item += NWV) {
    int y = item / NN;
    int d = item - y * NN;
    f32x4 r0g0, r0g1, r1g0, r1g1;
    int sec;
    if (y == 1) {
      agg_one2(1, d, lane, rowptr4, adj4, alpf, hbi, maxsrcE, r0g0, r0g1);
      agg_one2(3, d, lane, rowptr4, adj4, alpf, hbi, maxsrcE, r1g0, r1g1);
      f32x4 b1 = *(const f32x4*)(bias + 1 * 256 + lane * 4);
      f32x4 b3 = *(const f32x4*)(bias + 3 * 256 + lane * 4);
#pragma unroll
      for (int i = 0; i < 4; ++i) {
        r0g0[i] = 0.5f * (r0g0[i] + b1[i] + r1g0[i] + b3[i]);
        r0g1[i] = 0.5f * (r0g1[i] + b1[i] + r1g1[i] + b3[i]);
      }
      sec = 0;
    } else {
      int r = (y == 0) ? 0 : 2;
      agg_one2(r, d, lane, rowptr4, adj4, alpf, hbi, maxsrcE, r0g0, r0g1);
      f32x4 bv = *(const f32x4*)(bias + r * 256 + lane * 4);
#pragma unroll
      for (int i = 0; i < 4; ++i) { r0g0[i] += bv[i]; r0g1[i] += bv[i]; }
      sec = (y == 0) ? 1 : 2;
    }
    f32x4* op0 = (f32x4*)(out + ((size_t)(0 + sec) * NN + d) * 256 + lane * 4);
    f32x4* op1 = (f32x4*)(out + ((size_t)(3 + sec) * NN + d) * 256 + lane * 4);
    __builtin_nontemporal_store(r0g0, op0);
    __builtin_nontemporal_store(r0g1, op1);
  }
}

extern "C" void kernel_launch(void* const* d_in, const int* in_sizes, int n_in,
                              void* d_out, int out_size, void* d_ws, size_t ws_size,
                              hipStream_t stream) {
  (void)in_sizes; (void)n_in; (void)out_size; (void)ws_size;
  const float* x[6];
  for (int i = 0; i < 6; ++i) x[i] = (const float*)d_in[i];
  const float* W = (const float*)d_in[6];
  const float* att_src = (const float*)d_in[7];
  const float* att_dst = (const float*)d_in[8];
  const float* bias = (const float*)d_in[9];
  const int* ei[4] = {(const int*)d_in[10], (const int*)d_in[11],
                      (const int*)d_in[12], (const int*)d_in[13]};
  float* out = (float*)d_out;

  char* ws = (char*)d_ws;
  size_t off = 0;
  auto take = [&](size_t bytes) -> char* {
    char* p = ws + off;
    off += (bytes + 255) & ~(size_t)255;
    return p;
  };
  unsigned short* hbi = (unsigned short*)take(8ull * NN * 256 * 2);   // 163.8 MB
  float* alpf = (float*)take(3ull * 8 * NN * 16 * 4);                 // 61.4 MB
  unsigned short* wt2 = (unsigned short*)take(4ull * 8 * 256 * 32 * 2);
  unsigned short* weffb = (unsigned short*)take(8ull * 64 * 32 * 2);
  int* cnt = (int*)take(4ull * NN * 4);
  int* rowptr = (int*)take(4ull * (NN + 1) * 4);
  int* cursor = (int*)take(4ull * NN * 4);
  int* adj = (int*)take(4ull * EE * 4);
  unsigned* maxsrcE = (unsigned*)take(64ull * 4);

  k_prep<<<dim3(1714), 256, 0, stream>>>(W, att_src, att_dst, wt2, weffb, cnt, maxsrcE);
  k_hist<<<dim3((EE + 255) / 256, 4), 256, 0, stream>>>(ei[0], ei[1], ei[2], ei[3], cnt);
  k_scan<<<dim3(4), 1024, 0, stream>>>(cnt, rowptr, cursor);
  k_scatter<<<dim3((EE + 255) / 256, 4), 256, 0, stream>>>(ei[0], ei[1], ei[2], ei[3], cursor, adj);
  k_gemmb8<<<dim3(625, 8), 256, 0, stream>>>(x[0], x[1], x[2], x[3], x[4], x[5],
                                             wt2, weffb, hbi, alpf, maxsrcE);
  k_agg6<<<dim3(AGG_BLOCKS), 256, 0, stream>>>(rowptr, adj, alpf, hbi, bias, maxsrcE, out);
}